// Round 6
// baseline (1194.531 us; speedup 1.0000x reference)
//
#include <hip/hip_runtime.h>
#include <stdint.h>

// Problem constants (match reference)
#define NB   8
#define NP   16384
#define NG   512      // NUM_GROUPS
#define GS   32       // GROUP_SIZE
#define UPK  512      // UPSCALE_K
#define CTX  256      // CONTEXT

// float32 output layout (flat element offsets):
// groups (8,256,32,4) | centers (8,256,4) | emb_mask (8,256) | point_mask (8,256,32)
#define OFF_CENTERS (NB*CTX*GS*4)            // 262144
#define OFF_EMB     (OFF_CENTERS + NB*CTX*4) // 270336
#define OFF_PMASK   (OFF_EMB + NB*CTX)       // 272384

typedef unsigned long long u64;
typedef unsigned int u32;

// Monotonic float->uint key (preserves total order of floats)
__device__ __forceinline__ u32 fkey(float f) {
  union { float f; u32 u; } v; v.f = f;
  u32 s = v.u;
  return s ^ ((s & 0x80000000u) ? 0xFFFFFFFFu : 0x80000000u);
}

__device__ __forceinline__ int clampi(int x, int lo, int hi) {
  return x < lo ? lo : (x > hi ? hi : x);
}

// Strictly-unfused f32 squared distance, op order = np: ((dx*dx+dy*dy)+dz*dz).
// _rn intrinsics forbid FMA contraction (hipcc defaults -ffp-contract=fast).
__device__ __forceinline__ float dist2(float ax, float ay, float az,
                                       float bx, float by, float bz) {
  float dx = __fsub_rn(ax, bx);
  float dy = __fsub_rn(ay, by);
  float dz = __fsub_rn(az, bz);
  return __fadd_rn(__fadd_rn(__fmul_rn(dx, dx), __fmul_rn(dy, dy)),
                   __fmul_rn(dz, dz));
}

// ---------------------------------------------------------------------------
// Kernel 1: farthest point sampling. One block per batch, 511 sequential
// argmax steps. Coords + min-dist in registers; key = (dist, then min index)
// = np.argmax first-occurrence. Also zeroes group_len (replaces memset node).
// ---------------------------------------------------------------------------
#define FPS_T 1024
#define PPT   (NP / FPS_T)   // 16 points per thread

__global__ __launch_bounds__(FPS_T)
void fps_kernel(const float4* __restrict__ pts, const int* __restrict__ lengths,
                float4* __restrict__ centers_ws, int* __restrict__ group_len,
                float* __restrict__ out)
{
  const int b    = blockIdx.x;
  const int tid  = threadIdx.x;
  const int lane = tid & 63;
  const int wave = tid >> 6;
  const float4* p = pts + (size_t)b * NP;
  const int len = lengths[b];
  if (tid == 0) group_len[b] = 0;

  float px[PPT], py[PPT], pz[PPT], mind[PPT];
  u32 vmask = 0;
#pragma unroll
  for (int j = 0; j < PPT; j++) {
    int i = tid + j * FPS_T;          // strided ownership -> coalesced loads
    float4 q = p[i];
    px[j] = q.x; py[j] = q.y; pz[j] = q.z;
    mind[j] = 1e10f;
    if (i < len) vmask |= (1u << j);
  }

  __shared__ u64 sred[2][16];         // parity-buffered -> 1 barrier/step
  __shared__ int s_centers[NG];
  if (tid == 0) s_centers[0] = 0;     // start index = 0

  int last = 0;
  for (int it = 1; it < NG; it++) {
    float4 lp = p[last];              // broadcast load, L1-served
    u64 bk = 0;
#pragma unroll
    for (int j = 0; j < PPT; j++) {
      float d = dist2(px[j], py[j], pz[j], lp.x, lp.y, lp.z);
      float m = fminf(mind[j], d);
      mind[j] = m;
      if ((vmask >> j) & 1u) {
        int i = tid + j * FPS_T;
        u64 k = ((u64)fkey(m) << 32) | (u32)(~i);  // max val, then min idx
        if (k > bk) bk = k;
      }
    }
#pragma unroll
    for (int off = 32; off; off >>= 1) {
      u64 o = __shfl_down(bk, (unsigned)off, 64);
      if (o > bk) bk = o;
    }
    if (lane == 0) sred[it & 1][wave] = bk;
    __syncthreads();
    u64 m = sred[it & 1][0];
#pragma unroll
    for (int w = 1; w < 16; w++) { u64 o = sred[it & 1][w]; if (o > m) m = o; }
    last = clampi((int)(u32)(~(u32)m), 0, NP - 1);  // identical on all threads
    if (tid == 0) s_centers[it] = last;
  }
  __syncthreads();

  if (tid < NG) {
    int ci = clampi(s_centers[tid], 0, NP - 1);
    float4 q = p[ci];
    centers_ws[b * NG + tid] = q;
    if (tid < CTX) {                  // f32 copy of the full point
      ((float4*)(out + OFF_CENTERS))[b * CTX + tid] = q;
    }
  }
}

// ---------------------------------------------------------------------------
// Kernel 2: ball query (first-512-by-index candidates, strict-f32 test)
// + top-32 by energy (stable descending, min-candidate-pos tie-break).
// One block per (b,g).
// ---------------------------------------------------------------------------
#define BQ_T 256

__global__ __launch_bounds__(BQ_T)
void group_kernel(const float4* __restrict__ pts, const int* __restrict__ lengths,
                  const float4* __restrict__ centers_ws, int* __restrict__ group_len,
                  float* __restrict__ out)
{
  const int blk  = blockIdx.x;
  const int b    = blk >> 9;          // / NG
  const int g    = blk & (NG - 1);
  const int tid  = threadIdx.x;
  const int lane = tid & 63;
  const int wave = tid >> 6;
  const float4* p = pts + (size_t)b * NP;
  const int len = lengths[b];
  const float4 cc = centers_ws[b * NG + g];

  __shared__ u64 masks[256];          // per-64-chunk in-radius bitmasks
  __shared__ u32 scnt[256];
  __shared__ u32 spre[256];
  __shared__ float candE[UPK];
  __shared__ int   candI[UPK];
  __shared__ int   s_T;
  __shared__ u64   swin[2][4];

  // Pass 1: in-radius flags, index order preserved via ballot
  for (int step = 0; step < 64; step++) {
    int i = step * 256 + tid;         // chunk = step*4 + wave, bit = lane
    bool flag = false;
    if (i < len) {
      float4 q = p[i];
      float d = dist2(cc.x, cc.y, cc.z, q.x, q.y, q.z);
      flag = d < 0.25f;               // radius^2, strict <
    }
    u64 m = __ballot(flag);
    if (lane == 0) masks[step * 4 + wave] = m;
  }
  __syncthreads();

  // Block inclusive scan over 256 chunk counts
  u32 cnt = (u32)__popcll(masks[tid]);
  scnt[tid] = cnt;
  spre[tid] = cnt;
  __syncthreads();
  for (int off = 1; off < 256; off <<= 1) {
    u32 y = (tid >= off) ? spre[tid - off] : 0u;
    __syncthreads();
    spre[tid] += y;
    __syncthreads();
  }
  const u32 total = spre[255];

  if (g >= CTX) {                     // only "is group full" needed
    if (tid == 0 && total >= GS) atomicAdd(&group_len[b], 1);
    return;
  }

  const int ncand = (int)(total < UPK ? total : UPK);

  // Cap index T: index of the (UPK-1)-ranked in-radius point (first-512 rule)
  if (total > UPK) {
    u32 ex = spre[tid] - scnt[tid];
    if (ex <= (UPK - 1) && spre[tid] > (UPK - 1)) {   // exactly one thread
      u32 r = (UPK - 1) - ex;
      u64 m = masks[tid];
      for (u32 k = 0; k < r; k++) m &= m - 1;
      s_T = tid * 64 + ((int)__ffsll((unsigned long long)m) - 1);
    }
  } else if (tid == 0) {
    s_T = NP - 1;
  }
  __syncthreads();
  const int T = s_T;

  // Pass 2: compact (energy, idx) of candidates into LDS at exact rank
  for (int step = 0; step < 64; step++) {
    int i  = step * 256 + tid;
    int ch = step * 4 + wave;
    u64 m = masks[ch];
    if (((m >> lane) & 1ull) && i <= T) {
      u32 pos = ((spre[ch] - scnt[ch]) +
                 (u32)__popcll(m & ((1ull << lane) - 1ull))) & (UPK - 1);
      candE[pos] = ((const float*)p)[i * 4 + 3];   // energy channel, cache-hot
      candI[pos] = i;
    }
  }
  __syncthreads();

  // Top-32 by (energy desc, pos asc): 32 rounds of block argmax
  u64 k0 = 0, k1 = 0;
  const int i0 = tid, i1 = tid + 256;
  if (i0 < ncand) k0 = ((u64)fkey(candE[i0]) << 32) | (u32)(~i0);
  if (i1 < ncand) k1 = ((u64)fkey(candE[i1]) << 32) | (u32)(~i1);

  int pl = 0, mywin = -1, first = -1;
  for (int r = 0; r < GS; r++) {
    u64 bk = k0 > k1 ? k0 : k1;
#pragma unroll
    for (int off = 32; off; off >>= 1) {
      u64 o = __shfl_down(bk, (unsigned)off, 64);
      if (o > bk) bk = o;
    }
    if (lane == 0) swin[r & 1][wave] = bk;
    __syncthreads();
    u64 m = swin[r & 1][0];
#pragma unroll
    for (int w = 1; w < 4; w++) { u64 o = swin[r & 1][w]; if (o > m) m = o; }
    if (m) {
      int pos = (int)(u32)(~(u32)m) & (UPK - 1);
      int wi  = candI[pos];           // LDS broadcast
      if (pos == i0) k0 = 0;          // remove winner
      if (pos == i1) k1 = 0;
      if (r == 0) first = wi;         // group's top-1 index (for -1 fill)
      if (tid == r) mywin = wi;       // thread k records round-k winner
      pl++;
    }
  }

  const int base = b * CTX + g;
  if (tid < GS) {
    // fill_empty_indices: -1 -> group's first index (total>=1 always: the
    // center itself is in-radius). Clamp mirrors masked_gather's max(idx,0).
    int fi = clampi((mywin < 0) ? first : mywin, 0, NP - 1);
    float4 q = p[fi];
    ((float4*)out)[base * GS + tid] = q;
    out[OFF_PMASK + base * GS + tid] = (tid < pl) ? 1.0f : 0.0f;
  }
  if (tid == 0 && total >= GS) atomicAdd(&group_len[b], 1);
}

// ---------------------------------------------------------------------------
// Kernel 3: embedding mask from full-group counts
// ---------------------------------------------------------------------------
__global__ void emb_kernel(const int* __restrict__ group_len,
                           float* __restrict__ out)
{
  int i = blockIdx.x * blockDim.x + threadIdx.x;
  if (i < NB * CTX) {
    int b = i >> 8;
    int g = i & 255;
    out[OFF_EMB + i] = (g < group_len[b]) ? 1.0f : 0.0f;
  }
}

extern "C" void kernel_launch(void* const* d_in, const int* in_sizes, int n_in,
                              void* d_out, int out_size, void* d_ws, size_t ws_size,
                              hipStream_t stream)
{
  const float4* pts     = (const float4*)d_in[0];   // f32 (B,N,4)
  const int*    lengths = (const int*)d_in[1];
  float* out = (float*)d_out;

  float4* centers_ws = (float4*)d_ws;               // 8*512*16 B = 64 KB
  int*    group_len  = (int*)((char*)d_ws + (size_t)NB * NG * sizeof(float4));

  fps_kernel<<<NB, FPS_T, 0, stream>>>(pts, lengths, centers_ws, group_len, out);
  group_kernel<<<NB * NG, BQ_T, 0, stream>>>(pts, lengths, centers_ws, group_len, out);
  emb_kernel<<<(NB * CTX + 255) / 256, 256, 0, stream>>>(group_len, out);
}

// Round 7
// 892.258 us; speedup vs baseline: 1.3388x; 1.3388x over previous
//
#include <hip/hip_runtime.h>
#include <stdint.h>

// Problem constants (match reference)
#define NB   8
#define NP   16384
#define NG   512      // NUM_GROUPS
#define GS   32       // GROUP_SIZE
#define UPK  512      // UPSCALE_K
#define CTX  256      // CONTEXT

// float32 output layout (flat element offsets):
// groups (8,256,32,4) | centers (8,256,4) | emb_mask (8,256) | point_mask (8,256,32)
#define OFF_CENTERS (NB*CTX*GS*4)            // 262144
#define OFF_EMB     (OFF_CENTERS + NB*CTX*4) // 270336
#define OFF_PMASK   (OFF_EMB + NB*CTX)       // 272384

typedef unsigned long long u64;
typedef unsigned int u32;

// Monotonic float->uint key (full-range; needed for energies which can be <0)
__device__ __forceinline__ u32 fkey(float f) {
  union { float f; u32 u; } v; v.f = f;
  u32 s = v.u;
  return s ^ ((s & 0x80000000u) ? 0xFFFFFFFFu : 0x80000000u);
}

// Strictly-unfused f32 squared distance, op order = np: ((dx*dx+dy*dy)+dz*dz).
// _rn intrinsics forbid FMA contraction (hipcc defaults -ffp-contract=fast).
__device__ __forceinline__ float dist2(float ax, float ay, float az,
                                       float bx, float by, float bz) {
  float dx = __fsub_rn(ax, bx);
  float dy = __fsub_rn(ay, by);
  float dz = __fsub_rn(az, bz);
  return __fadd_rn(__fadd_rn(__fmul_rn(dx, dx), __fmul_rn(dy, dy)),
                   __fmul_rn(dz, dz));
}

// ---------------------------------------------------------------------------
// Kernel 1: farthest point sampling. One block per batch, 511 sequential
// argmax steps, VALU-issue-bound on 8 CUs. Inner loop = 12 instr/point:
// distances >= 0 so raw f32 bits are order-preserving -> no fkey, no u64 per
// point; per-thread (tmax, tj) via strict > (keeps earliest j = min index).
// Invalid points (i >= len) alias point 0's coords: their mind becomes
// exactly 0 after iteration 1, so they can never win the argmax (valid
// minds are > 0 for distinct points) — removes the validity mask from the
// hot loop. u64 key (bits<<32 | ~gidx) built once per iter; tie-break =
// global min index = np.argmax first occurrence.
// ---------------------------------------------------------------------------
#define FPS_T 1024
#define PPT   (NP / FPS_T)   // 16 points per thread

__global__ __launch_bounds__(FPS_T)
void fps_kernel(const float4* __restrict__ pts, const int* __restrict__ lengths,
                float4* __restrict__ centers_ws, int* __restrict__ group_len,
                float* __restrict__ out)
{
  const int b    = blockIdx.x;
  const int tid  = threadIdx.x;
  const int lane = tid & 63;
  const int wave = tid >> 6;
  const float4* p = pts + (size_t)b * NP;
  const int len = lengths[b];
  if (tid == 0) group_len[b] = 0;

  const float4 q0 = p[0];
  float px[PPT], py[PPT], pz[PPT], mind[PPT];
#pragma unroll
  for (int j = 0; j < PPT; j++) {
    int i = tid + j * FPS_T;          // strided ownership -> coalesced loads
    float4 q = p[i];
    if (i >= len) q = q0;             // invalid -> alias of point 0
    px[j] = q.x; py[j] = q.y; pz[j] = q.z;
    mind[j] = 1e10f;
  }

  __shared__ u64 sred[2][16];         // parity-buffered -> 1 barrier/step
  __shared__ int s_centers[NG];
  if (tid == 0) s_centers[0] = 0;     // start index = 0

  int last = 0;
  for (int it = 1; it < NG; it++) {
    float4 lp = p[last];              // broadcast load, L1-served
    float tmax = -1.0f; int tj = 0;
#pragma unroll
    for (int j = 0; j < PPT; j++) {
      float d = dist2(px[j], py[j], pz[j], lp.x, lp.y, lp.z);
      float m = fminf(mind[j], d);
      mind[j] = m;
      bool c = m > tmax;              // strict > keeps earliest j
      tmax = c ? m : tmax;
      tj   = c ? j : tj;
    }
    int gidx = tid + (tj << 10);      // j asc => global idx asc within thread
    u64 key = ((u64)__float_as_uint(tmax) << 32) | (u32)(~gidx);
#pragma unroll
    for (int off = 32; off; off >>= 1) {
      u64 o = __shfl_down(key, (unsigned)off, 64);
      if (o > key) key = o;
    }
    if (lane == 0) sred[it & 1][wave] = key;
    __syncthreads();
    u64 k2 = sred[it & 1][lane & 15]; // all lanes join the 16-slot butterfly
#pragma unroll
    for (int off = 8; off; off >>= 1) {
      u64 o = __shfl_xor(k2, (unsigned)off, 64);
      if (o > k2) k2 = o;
    }
    last = (int)(~(u32)k2) & (NP - 1);
    if (tid == 0) s_centers[it] = last;
  }
  __syncthreads();

  if (tid < NG) {
    int ci = s_centers[tid] & (NP - 1);
    float4 q = p[ci];
    centers_ws[b * NG + tid] = q;
    if (tid < CTX) {
      ((float4*)(out + OFF_CENTERS))[b * CTX + tid] = q;
    }
  }
}

// ---------------------------------------------------------------------------
// Kernel 2: ball query (first-512-by-index candidates, strict-f32 test)
// + top-32 by energy. Swizzled so batch b owns XCD b (blk&7) -> per-XCD
// L2-resident point data. g >= CTX groups take a count-only fast path.
// Heavy path: ballot masks -> shfl_up prefix scan (1 barrier) -> compact ->
// single-wave barrier-free top-32 (u64 key = fkeyE<<32 | ~pos; pos encodes
// owner lane+slot so the kill step needs no index tracking).
// ---------------------------------------------------------------------------
#define BQ_T 256

__global__ __launch_bounds__(BQ_T)
void group_kernel(const float4* __restrict__ pts, const int* __restrict__ lengths,
                  const float4* __restrict__ centers_ws, int* __restrict__ group_len,
                  float* __restrict__ out)
{
  const int blk  = blockIdx.x;
  const int b    = blk & (NB - 1);    // XCD affinity (blockIdx % 8 round-robin)
  const int g    = blk >> 3;
  const int tid  = threadIdx.x;
  const int lane = tid & 63;
  const int wave = tid >> 6;
  const float4* p = pts + (size_t)b * NP;
  const int len = lengths[b];
  const float4 cc = centers_ws[b * NG + g];

  __shared__ u64 masks[256];          // per-64-chunk in-radius bitmasks
  __shared__ u32 scnt[256];
  __shared__ u32 spre[256];
  __shared__ u32 swsum[4];
  __shared__ float candE[UPK];
  __shared__ int   candI[UPK];
  __shared__ int   s_T, s_pl;
  __shared__ int   s_win[GS];

  if (g >= CTX) {                     // count-only: is this group full?
    u32 c = 0;
    for (int step = 0; step < 64; step++) {
      int i = step * 256 + tid;
      if (i < len) {
        float4 q = p[i];
        float d = dist2(cc.x, cc.y, cc.z, q.x, q.y, q.z);
        c += (d < 0.25f) ? 1u : 0u;
      }
    }
#pragma unroll
    for (int off = 32; off; off >>= 1) c += __shfl_down(c, (unsigned)off, 64);
    if (lane == 0) swsum[wave] = c;
    __syncthreads();
    if (tid == 0) {
      u32 total = swsum[0] + swsum[1] + swsum[2] + swsum[3];
      if (total >= GS) atomicAdd(&group_len[b], 1);
    }
    return;
  }

  // Pass 1: in-radius flags, index order preserved via ballot
  for (int step = 0; step < 64; step++) {
    int i = step * 256 + tid;         // chunk = step*4 + wave, bit = lane
    bool flag = false;
    if (i < len) {
      float4 q = p[i];
      float d = dist2(cc.x, cc.y, cc.z, q.x, q.y, q.z);
      flag = d < 0.25f;               // radius^2, strict <
    }
    u64 m = __ballot(flag);
    if (lane == 0) masks[step * 4 + wave] = m;
  }
  __syncthreads();

  // Prefix scan over 256 chunk counts: shfl_up within wave + 4-wave offset
  u32 cnt = (u32)__popcll(masks[tid]);
  u32 s = cnt;
#pragma unroll
  for (int off = 1; off < 64; off <<= 1) {
    u32 o = __shfl_up(s, (unsigned)off, 64);
    if (lane >= off) s += o;
  }
  if (lane == 63) swsum[wave] = s;
  __syncthreads();
  u32 woff = 0;
#pragma unroll
  for (int w = 0; w < 4; w++) woff += (w < wave) ? swsum[w] : 0u;
  const u32 total = swsum[0] + swsum[1] + swsum[2] + swsum[3];
  const u32 incl = s + woff;          // block-inclusive prefix for chunk tid
  scnt[tid] = cnt;
  spre[tid] = incl;

  // Cap index T: index of the (UPK-1)-ranked in-radius point (first-512 rule)
  if (total > UPK) {
    u32 ex = incl - cnt;
    if (ex <= (UPK - 1) && incl > (UPK - 1)) {        // exactly one thread
      u32 r = (UPK - 1) - ex;
      u64 m = masks[tid];
      for (u32 k = 0; k < r; k++) m &= m - 1;
      s_T = tid * 64 + ((int)__ffsll((unsigned long long)m) - 1);
    }
  } else if (tid == 0) {
    s_T = NP - 1;
  }
  __syncthreads();                    // covers spre/scnt/s_T
  const int T = s_T;

  // Pass 2: compact (energy, idx) of candidates into LDS at exact rank
  for (int step = 0; step < 64; step++) {
    int i  = step * 256 + tid;
    int ch = step * 4 + wave;
    u64 m = masks[ch];
    if (((m >> lane) & 1ull) && i <= T) {
      u32 pos = ((spre[ch] - scnt[ch]) +
                 (u32)__popcll(m & ((1ull << lane) - 1ull))) & (UPK - 1);
      candE[pos] = ((const float*)p)[i * 4 + 3];   // energy channel
      candI[pos] = i;
    }
  }
  __syncthreads();

  const int ncand = (int)(total < UPK ? total : UPK);

  // Top-32 by (energy desc, pos asc): single wave, barrier-free rounds
  if (wave == 0) {
    u64 k[8];
#pragma unroll
    for (int t = 0; t < 8; t++) {
      int ci = lane + t * 64;
      k[t] = (ci < ncand) ? (((u64)fkey(candE[ci]) << 32) | (u32)(~ci)) : 0ull;
    }
    int pl = 0;
    for (int r = 0; r < GS; r++) {
      u64 bm = k[0];
#pragma unroll
      for (int t = 1; t < 8; t++) if (k[t] > bm) bm = k[t];
#pragma unroll
      for (int off = 32; off; off >>= 1) {
        u64 o = __shfl_xor(bm, (unsigned)off, 64);
        if (o > bm) bm = o;
      }
      if (bm == 0) break;             // wave-uniform: no candidates left
      int pos = (int)(~(u32)bm) & (UPK - 1);
      if (lane == 0) s_win[r] = candI[pos];
      int ol = pos & 63, ot = pos >> 6;
#pragma unroll
      for (int t = 0; t < 8; t++)     // kill winner (owner = lane ol, slot ot)
        if (t == ot && lane == ol) k[t] = 0;
      pl = r + 1;
    }
    if (lane == 0) {
      int f0 = (pl > 0) ? s_win[0] : 0;   // fill_empty_indices (pl>=1 always:
      for (int r = pl; r < GS; r++) s_win[r] = f0;  // center is in-radius)
      s_pl = pl;
    }
  }
  __syncthreads();

  const int base = b * CTX + g;
  if (tid < GS) {
    int fi = s_win[tid] & (NP - 1);
    float4 q = p[fi];
    ((float4*)out)[base * GS + tid] = q;
    out[OFF_PMASK + base * GS + tid] = (tid < s_pl) ? 1.0f : 0.0f;
  }
  if (tid == 0 && total >= GS) atomicAdd(&group_len[b], 1);
}

// ---------------------------------------------------------------------------
// Kernel 3: embedding mask from full-group counts
// ---------------------------------------------------------------------------
__global__ void emb_kernel(const int* __restrict__ group_len,
                           float* __restrict__ out)
{
  int i = blockIdx.x * blockDim.x + threadIdx.x;
  if (i < NB * CTX) {
    int b = i >> 8;
    int g = i & 255;
    out[OFF_EMB + i] = (g < group_len[b]) ? 1.0f : 0.0f;
  }
}

extern "C" void kernel_launch(void* const* d_in, const int* in_sizes, int n_in,
                              void* d_out, int out_size, void* d_ws, size_t ws_size,
                              hipStream_t stream)
{
  const float4* pts     = (const float4*)d_in[0];   // f32 (B,N,4)
  const int*    lengths = (const int*)d_in[1];
  float* out = (float*)d_out;

  float4* centers_ws = (float4*)d_ws;               // 8*512*16 B = 64 KB
  int*    group_len  = (int*)((char*)d_ws + (size_t)NB * NG * sizeof(float4));

  fps_kernel<<<NB, FPS_T, 0, stream>>>(pts, lengths, centers_ws, group_len, out);
  group_kernel<<<NB * NG, BQ_T, 0, stream>>>(pts, lengths, centers_ws, group_len, out);
  emb_kernel<<<(NB * CTX + 255) / 256, 256, 0, stream>>>(group_len, out);
}

// Round 8
// 837.517 us; speedup vs baseline: 1.4263x; 1.0654x over previous
//
#include <hip/hip_runtime.h>
#include <stdint.h>

// Problem constants (match reference)
#define NB   8
#define NP   16384
#define NG   512      // NUM_GROUPS
#define GS   32       // GROUP_SIZE
#define UPK  512      // UPSCALE_K
#define CTX  256      // CONTEXT

// float32 output layout (flat element offsets):
// groups (8,256,32,4) | centers (8,256,4) | emb_mask (8,256) | point_mask (8,256,32)
#define OFF_CENTERS (NB*CTX*GS*4)            // 262144
#define OFF_EMB     (OFF_CENTERS + NB*CTX*4) // 270336
#define OFF_PMASK   (OFF_EMB + NB*CTX)       // 272384

typedef unsigned long long u64;
typedef unsigned int u32;

// Monotonic float->uint key (full-range; needed for energies which can be <0)
__device__ __forceinline__ u32 fkey(float f) {
  union { float f; u32 u; } v; v.f = f;
  u32 s = v.u;
  return s ^ ((s & 0x80000000u) ? 0xFFFFFFFFu : 0x80000000u);
}

// Strictly-unfused f32 squared distance, op order = np: ((dx*dx+dy*dy)+dz*dz).
// _rn intrinsics forbid FMA contraction (hipcc defaults -ffp-contract=fast).
__device__ __forceinline__ float dist2(float ax, float ay, float az,
                                       float bx, float by, float bz) {
  float dx = __fsub_rn(ax, bx);
  float dy = __fsub_rn(ay, by);
  float dz = __fsub_rn(az, bz);
  return __fadd_rn(__fadd_rn(__fmul_rn(dx, dx), __fmul_rn(dy, dy)),
                   __fmul_rn(dz, dz));
}

// u64 max-combine with a DPP-moved copy. update_dpp keeps `old` (own value)
// for invalid source lanes / write-disabled rows, so the max is a no-op
// there — safe for reductions. VALU-latency cross-lane (no LDS pipe).
template<int CTRL, int RM>
__device__ __forceinline__ u64 dpp_max_u64(u64 k) {
  int lo = (int)(u32)k, hi = (int)(u32)(k >> 32);
  int mlo = __builtin_amdgcn_update_dpp(lo, lo, CTRL, RM, 0xf, false);
  int mhi = __builtin_amdgcn_update_dpp(hi, hi, CTRL, RM, 0xf, false);
  u64 o = ((u64)(u32)mhi << 32) | (u32)mlo;
  return o > k ? o : k;
}

// Full wave64 max reduce: result valid in lane 63.
__device__ __forceinline__ u64 wave_max_u64(u64 k) {
  k = dpp_max_u64<0x111, 0xf>(k);   // row_shr:1
  k = dpp_max_u64<0x112, 0xf>(k);   // row_shr:2
  k = dpp_max_u64<0x114, 0xf>(k);   // row_shr:4
  k = dpp_max_u64<0x118, 0xf>(k);   // row_shr:8  -> lane15/31/47/63 = row max
  k = dpp_max_u64<0x142, 0xa>(k);   // row_bcast:15 -> lane31, lane63 merge
  k = dpp_max_u64<0x143, 0xc>(k);   // row_bcast:31 -> lane63 = wave max
  return k;
}

__device__ __forceinline__ u64 read_lane_u64(u64 k, int lane) {
  u32 lo = (u32)__builtin_amdgcn_readlane((int)(u32)k, lane);
  u32 hi = (u32)__builtin_amdgcn_readlane((int)(u32)(k >> 32), lane);
  return ((u64)hi << 32) | lo;
}

// ---------------------------------------------------------------------------
// Kernel 1: farthest point sampling. One block per batch, 511 sequential
// argmax steps on one CU (VALU-issue + reduce-latency bound). Inner loop:
// strictly-unfused dists, pairwise-grouped for SLP/VOP3P; per-thread
// (tmax, tj) argmax via strict > (keeps earliest j = min index). Invalid
// points alias point 0 -> mind becomes exactly 0 after iter 1, never wins.
// Reductions: wave-level DPP (lane63) -> 16 LDS slots (parity-buffered,
// 1 barrier/iter) -> 4-step DPP row reduce over replicated slots.
// ---------------------------------------------------------------------------
#define FPS_T 1024
#define PPT   (NP / FPS_T)   // 16 points per thread

__global__ __launch_bounds__(FPS_T)
void fps_kernel(const float4* __restrict__ pts, const int* __restrict__ lengths,
                float4* __restrict__ centers_ws, int* __restrict__ group_len,
                float* __restrict__ out)
{
  const int b    = blockIdx.x;
  const int tid  = threadIdx.x;
  const int lane = tid & 63;
  const int wave = tid >> 6;
  const float4* p = pts + (size_t)b * NP;
  const int len = lengths[b];
  if (tid == 0) group_len[b] = 0;

  const float4 q0 = p[0];
  float px[PPT], py[PPT], pz[PPT], mind[PPT];
#pragma unroll
  for (int j = 0; j < PPT; j++) {
    int i = tid + j * FPS_T;          // strided ownership -> coalesced loads
    float4 q = p[i];
    if (i >= len) q = q0;             // invalid -> alias of point 0
    px[j] = q.x; py[j] = q.y; pz[j] = q.z;
    mind[j] = 1e10f;
  }

  __shared__ u64 sred[2][16];         // parity-buffered -> 1 barrier/step
  __shared__ int s_centers[NG];
  if (tid == 0) s_centers[0] = 0;     // start index = 0

  int last = 0;
  for (int it = 1; it < NG; it++) {
    float4 lp = p[last];              // broadcast load (L2-served)
    float tmax = -1.0f; int tj = 0;
#pragma unroll
    for (int h = 0; h < PPT / 2; h++) {       // pairwise: SLP -> v_pk_* f32
      const int ja = 2 * h, jb = 2 * h + 1;
      float dxa = __fsub_rn(px[ja], lp.x), dxb = __fsub_rn(px[jb], lp.x);
      float dya = __fsub_rn(py[ja], lp.y), dyb = __fsub_rn(py[jb], lp.y);
      float dza = __fsub_rn(pz[ja], lp.z), dzb = __fsub_rn(pz[jb], lp.z);
      float sa = __fmul_rn(dxa, dxa),      sb = __fmul_rn(dxb, dxb);
      float ta = __fmul_rn(dya, dya),      tb = __fmul_rn(dyb, dyb);
      float ua = __fmul_rn(dza, dza),      ub = __fmul_rn(dzb, dzb);
      float va = __fadd_rn(sa, ta),        vb = __fadd_rn(sb, tb);
      float da = __fadd_rn(va, ua),        db = __fadd_rn(vb, ub);
      float ma = fminf(mind[ja], da);
      float mb = fminf(mind[jb], db);
      mind[ja] = ma; mind[jb] = mb;
      bool ca = ma > tmax;              // strict > keeps earliest j
      tmax = ca ? ma : tmax;
      tj   = ca ? ja : tj;
      bool cb = mb > tmax;
      tmax = cb ? mb : tmax;
      tj   = cb ? jb : tj;
    }
    int gidx = tid + (tj << 10);      // j asc => global idx asc within thread
    u64 key = ((u64)__float_as_uint(tmax) << 32) | (u32)(~gidx);
    key = wave_max_u64(key);          // lane 63 has wave winner
    u64 wkey = read_lane_u64(key, 63);
    if (lane == 0) sred[it & 1][wave] = wkey;
    __syncthreads();
    u64 k2 = sred[it & 1][lane & 15]; // replicated every 16 lanes
    k2 = dpp_max_u64<0x111, 0xf>(k2);
    k2 = dpp_max_u64<0x112, 0xf>(k2);
    k2 = dpp_max_u64<0x114, 0xf>(k2);
    k2 = dpp_max_u64<0x118, 0xf>(k2); // lane15 (every row) = block winner
    u64 bk = read_lane_u64(k2, 15);
    last = (int)(~(u32)bk) & (NP - 1);
    if (tid == 0) s_centers[it] = last;
  }
  __syncthreads();

  if (tid < NG) {
    int ci = s_centers[tid] & (NP - 1);
    float4 q = p[ci];
    centers_ws[b * NG + tid] = q;
    if (tid < CTX) {
      ((float4*)(out + OFF_CENTERS))[b * CTX + tid] = q;
    }
  }
}

// ---------------------------------------------------------------------------
// Kernel 2: ball query (first-512-by-index candidates, strict-f32 test)
// + top-32 by energy. Swizzled so batch b owns XCD b (blk&7) -> per-XCD
// L2-resident point data. g >= CTX groups take a count-only fast path.
// Heavy path: ballot masks -> shfl_up prefix scan (1 barrier) -> compact ->
// single-wave barrier-free top-32 (u64 key = fkeyE<<32 | ~pos; pos encodes
// owner lane+slot so the kill step needs no index tracking).
// ---------------------------------------------------------------------------
#define BQ_T 256

__global__ __launch_bounds__(BQ_T)
void group_kernel(const float4* __restrict__ pts, const int* __restrict__ lengths,
                  const float4* __restrict__ centers_ws, int* __restrict__ group_len,
                  float* __restrict__ out)
{
  const int blk  = blockIdx.x;
  const int b    = blk & (NB - 1);    // XCD affinity (blockIdx % 8 round-robin)
  const int g    = blk >> 3;
  const int tid  = threadIdx.x;
  const int lane = tid & 63;
  const int wave = tid >> 6;
  const float4* p = pts + (size_t)b * NP;
  const int len = lengths[b];
  const float4 cc = centers_ws[b * NG + g];

  __shared__ u64 masks[256];          // per-64-chunk in-radius bitmasks
  __shared__ u32 scnt[256];
  __shared__ u32 spre[256];
  __shared__ u32 swsum[4];
  __shared__ float candE[UPK];
  __shared__ int   candI[UPK];
  __shared__ int   s_T, s_pl;
  __shared__ int   s_win[GS];

  if (g >= CTX) {                     // count-only: is this group full?
    u32 c = 0;
    for (int step = 0; step < 64; step++) {
      int i = step * 256 + tid;
      if (i < len) {
        float4 q = p[i];
        float d = dist2(cc.x, cc.y, cc.z, q.x, q.y, q.z);
        c += (d < 0.25f) ? 1u : 0u;
      }
    }
#pragma unroll
    for (int off = 32; off; off >>= 1) c += __shfl_down(c, (unsigned)off, 64);
    if (lane == 0) swsum[wave] = c;
    __syncthreads();
    if (tid == 0) {
      u32 total = swsum[0] + swsum[1] + swsum[2] + swsum[3];
      if (total >= GS) atomicAdd(&group_len[b], 1);
    }
    return;
  }

  // Pass 1: in-radius flags, index order preserved via ballot
  for (int step = 0; step < 64; step++) {
    int i = step * 256 + tid;         // chunk = step*4 + wave, bit = lane
    bool flag = false;
    if (i < len) {
      float4 q = p[i];
      float d = dist2(cc.x, cc.y, cc.z, q.x, q.y, q.z);
      flag = d < 0.25f;               // radius^2, strict <
    }
    u64 m = __ballot(flag);
    if (lane == 0) masks[step * 4 + wave] = m;
  }
  __syncthreads();

  // Prefix scan over 256 chunk counts: shfl_up within wave + 4-wave offset
  u32 cnt = (u32)__popcll(masks[tid]);
  u32 s = cnt;
#pragma unroll
  for (int off = 1; off < 64; off <<= 1) {
    u32 o = __shfl_up(s, (unsigned)off, 64);
    if (lane >= off) s += o;
  }
  if (lane == 63) swsum[wave] = s;
  __syncthreads();
  u32 woff = 0;
#pragma unroll
  for (int w = 0; w < 4; w++) woff += (w < wave) ? swsum[w] : 0u;
  const u32 total = swsum[0] + swsum[1] + swsum[2] + swsum[3];
  const u32 incl = s + woff;          // block-inclusive prefix for chunk tid
  scnt[tid] = cnt;
  spre[tid] = incl;

  // Cap index T: index of the (UPK-1)-ranked in-radius point (first-512 rule)
  if (total > UPK) {
    u32 ex = incl - cnt;
    if (ex <= (UPK - 1) && incl > (UPK - 1)) {        // exactly one thread
      u32 r = (UPK - 1) - ex;
      u64 m = masks[tid];
      for (u32 k = 0; k < r; k++) m &= m - 1;
      s_T = tid * 64 + ((int)__ffsll((unsigned long long)m) - 1);
    }
  } else if (tid == 0) {
    s_T = NP - 1;
  }
  __syncthreads();                    // covers spre/scnt/s_T
  const int T = s_T;

  // Pass 2: compact (energy, idx) of candidates into LDS at exact rank
  for (int step = 0; step < 64; step++) {
    int i  = step * 256 + tid;
    int ch = step * 4 + wave;
    u64 m = masks[ch];
    if (((m >> lane) & 1ull) && i <= T) {
      u32 pos = ((spre[ch] - scnt[ch]) +
                 (u32)__popcll(m & ((1ull << lane) - 1ull))) & (UPK - 1);
      candE[pos] = ((const float*)p)[i * 4 + 3];   // energy channel
      candI[pos] = i;
    }
  }
  __syncthreads();

  const int ncand = (int)(total < UPK ? total : UPK);

  // Top-32 by (energy desc, pos asc): single wave, barrier-free rounds
  if (wave == 0) {
    u64 k[8];
#pragma unroll
    for (int t = 0; t < 8; t++) {
      int ci = lane + t * 64;
      k[t] = (ci < ncand) ? (((u64)fkey(candE[ci]) << 32) | (u32)(~ci)) : 0ull;
    }
    int pl = 0;
    for (int r = 0; r < GS; r++) {
      u64 bm = k[0];
#pragma unroll
      for (int t = 1; t < 8; t++) if (k[t] > bm) bm = k[t];
#pragma unroll
      for (int off = 32; off; off >>= 1) {
        u64 o = __shfl_xor(bm, (unsigned)off, 64);
        if (o > bm) bm = o;
      }
      if (bm == 0) break;             // wave-uniform: no candidates left
      int pos = (int)(~(u32)bm) & (UPK - 1);
      if (lane == 0) s_win[r] = candI[pos];
      int ol = pos & 63, ot = pos >> 6;
#pragma unroll
      for (int t = 0; t < 8; t++)     // kill winner (owner = lane ol, slot ot)
        if (t == ot && lane == ol) k[t] = 0;
      pl = r + 1;
    }
    if (lane == 0) {
      int f0 = (pl > 0) ? s_win[0] : 0;   // fill_empty_indices (pl>=1 always:
      for (int r = pl; r < GS; r++) s_win[r] = f0;  // center is in-radius)
      s_pl = pl;
    }
  }
  __syncthreads();

  const int base = b * CTX + g;
  if (tid < GS) {
    int fi = s_win[tid] & (NP - 1);
    float4 q = p[fi];
    ((float4*)out)[base * GS + tid] = q;
    out[OFF_PMASK + base * GS + tid] = (tid < s_pl) ? 1.0f : 0.0f;
  }
  if (tid == 0 && total >= GS) atomicAdd(&group_len[b], 1);
}

// ---------------------------------------------------------------------------
// Kernel 3: embedding mask from full-group counts
// ---------------------------------------------------------------------------
__global__ void emb_kernel(const int* __restrict__ group_len,
                           float* __restrict__ out)
{
  int i = blockIdx.x * blockDim.x + threadIdx.x;
  if (i < NB * CTX) {
    int b = i >> 8;
    int g = i & 255;
    out[OFF_EMB + i] = (g < group_len[b]) ? 1.0f : 0.0f;
  }
}

extern "C" void kernel_launch(void* const* d_in, const int* in_sizes, int n_in,
                              void* d_out, int out_size, void* d_ws, size_t ws_size,
                              hipStream_t stream)
{
  const float4* pts     = (const float4*)d_in[0];   // f32 (B,N,4)
  const int*    lengths = (const int*)d_in[1];
  float* out = (float*)d_out;

  float4* centers_ws = (float4*)d_ws;               // 8*512*16 B = 64 KB
  int*    group_len  = (int*)((char*)d_ws + (size_t)NB * NG * sizeof(float4));

  fps_kernel<<<NB, FPS_T, 0, stream>>>(pts, lengths, centers_ws, group_len, out);
  group_kernel<<<NB * NG, BQ_T, 0, stream>>>(pts, lengths, centers_ws, group_len, out);
  emb_kernel<<<(NB * CTX + 255) / 256, 256, 0, stream>>>(group_len, out);
}